// Round 16
// baseline (97.873 us; speedup 1.0000x reference)
//
#include <hip/hip_runtime.h>
#include <climits>
#include <cmath>

// YOLOv9 loss forward.  B=32 T=64 A=8400 C=80.
// r8 structure (champion, 80.06us) with LAZY CLS EVALUATION in k_topk:
// top-k over tm = i6*sqrt(sigmoid(cls)) prunes cls gathers via tm <= i6.
//   K1 k_topk     : enum i6 only -> top10 by i6 -> threshold -> sparse cls
//                   eval (i6 >= thr) -> top10 by tm   [exact, see proof]
//   K2 k_resolve  : one wave per candidate entry (wave-scan dedup)
//   K3 k_bce_sums : blocks [0,2048) softplus sums; [2048,2080) batch sums
//   K4 k_final    : combine -> out

#define NB 32
#define NT 64
#define NA 8400
#define NC 80
#define KTOP 10
#define NE (NT * KTOP)   // 640 entries per batch
#define CAP 1024
#define EPSF 1e-7f
#define INV_PI2 0.40528473456935108577f  // 4/pi^2
#define LOG2E_F 1.44269504088896340736f
#define LN2_F   0.69314718055994530942f
#define BCE_BLOCKS 2048

__device__ __forceinline__ float atan_wh(float x1, float y1, float x2, float y2) {
  return atanf((x2 - x1) / (y2 - y1 + EPSF));
}

__device__ __forceinline__ float ciou_pair(
    float ax1, float ay1, float ax2, float ay2, float atA,
    float bx1, float by1, float bx2, float by2, float atB)
{
  float xi1 = fmaxf(ax1, bx1), yi1 = fmaxf(ay1, by1);
  float xi2 = fminf(ax2, bx2), yi2 = fminf(ay2, by2);
  float inter = fmaxf(xi2 - xi1, 0.f) * fmaxf(yi2 - yi1, 0.f);
  float a1 = (ax2 - ax1) * (ay2 - ay1);
  float a2 = (bx2 - bx1) * (by2 - by1);
  float iou = inter / (a1 + a2 - inter + EPSF);
  float dcx = (ax2 + ax1) * 0.5f - (bx2 + bx1) * 0.5f;
  float dcy = (ay2 + ay1) * 0.5f - (by2 + by1) * 0.5f;
  float cent = dcx * dcx + dcy * dcy;
  float cw = fmaxf(ax2, bx2) - fminf(ax1, bx1);
  float ch = fmaxf(ay2, by2) - fminf(ay1, by1);
  float diag = cw * cw + ch * ch + EPSF;
  float dv = atA - atB;
  float v = INV_PI2 * dv * dv;
  float alpha = v / (v - iou + 1.f + EPSF);
  return iou - cent / diag - alpha * v;
}

// Fast softplus on the native transcendental pipe (verified absmax 0.0 r7-r15).
__device__ __forceinline__ float softplus_fast(float x) {
  float e = exp2f(-LOG2E_F * fabsf(x));     // v_exp_f32
  float l = __log2f(1.f + e);               // v_log_f32
  return fmaxf(x, 0.f) + LN2_F * l;
}

// ---- K1: per (b,t) row: lazy-cls top-10 ----------------------------------
// Proof of exactness: tm = i6*sqrt(sig) <= i6.  Let thr = min tm of the
// top-10-by-i6 set S (|S|=10 when n>=10).  True tenth-best tm >= thr (S gives
// 10 values >= thr).  Any candidate in the true top-10 has tm >= thr, hence
// i6 >= tm >= thr -> it is evaluated.  Excluded (i6 < thr strictly) have
// tm <= i6 < thr: cannot displace nor tie.  Ties at thr are included.
__global__ __launch_bounds__(256) void k_topk(
    const float* __restrict__ target,   // [B,T,5]
    const float* __restrict__ pcls,     // [B,A,C]
    const float* __restrict__ pbox,     // [B,A,4]
    float* __restrict__ top_val, int* __restrict__ top_idx,
    float* __restrict__ top_iou,
    unsigned* __restrict__ mtg, unsigned* __restrict__ mig)
{
  int row = blockIdx.x;            // b*NT + t   (grid is exactly NB*NT)
  int tid = threadIdx.x;
  if (tid == 0) { mtg[row] = 0u; mig[row] = 0u; }  // zero max tables
  int b = row >> 6;
  const float* tg = target + (size_t)row * 5;
  float tcf = tg[0];
  float x1 = tg[1], y1 = tg[2], x2 = tg[3], y2 = tg[4];
  int tc = (int)tcf; tc = tc < 0 ? 0 : (tc > NC - 1 ? NC - 1 : tc);
  float atan_t = atan_wh(x1, y1, x2, y2);

  __shared__ int s_n;
  __shared__ float s_i6[CAP];
  __shared__ float s_tm[CAP];
  __shared__ int s_idx[CAP];
  __shared__ float xw_v[4];  __shared__ int xw_a[4];
  __shared__ float w_val[KTOP]; __shared__ int w_idx[KTOP];
  __shared__ float s_thr;
  if (tid == 0) s_n = 0;
  __syncthreads();

  const float* pb_b = pbox + (size_t)b * NA * 4;
  const float* pc_b = pcls + (size_t)b * NA * NC;

  // Phase 1: analytic rect enum; compute i6 ONLY (no pcls gather).
  // Anchors: 3 meshgrids, level l: n_l x n_l at (i+0.5)*s_l; s={8,16,32},
  // n={80,40,20}, base={0,6400,8000}; a = base + iy*n + ix.
#define LEVEL_LOOP(S, N, BASE)                                              \
  {                                                                         \
    const float s = (float)(S);                                             \
    int ix0 = (int)floorf(x1 / s - 0.5f); if (ix0 < 0) ix0 = 0;             \
    int ix1 = (int)ceilf (x2 / s - 0.5f); if (ix1 > (N)-1) ix1 = (N)-1;     \
    int iy0 = (int)floorf(y1 / s - 0.5f); if (iy0 < 0) iy0 = 0;             \
    int iy1 = (int)ceilf (y2 / s - 0.5f); if (iy1 > (N)-1) iy1 = (N)-1;     \
    int w = ix1 - ix0 + 1; w = w < 0 ? 0 : w;                               \
    int h = iy1 - iy0 + 1; h = h < 0 ? 0 : h;                               \
    int cnt = w * h;                                                        \
    for (int k = tid; k < cnt; k += 256) {                                  \
      int ix = ix0 + k % w;                                                 \
      int iy = iy0 + k / w;                                                 \
      float anx = (ix + 0.5f) * s;                                          \
      float any_ = (iy + 0.5f) * s;                                         \
      if (x1 < anx && anx < x2 && y1 < any_ && any_ < y2) {                 \
        int a = (BASE) + iy * (N) + ix;                                     \
        float4 bb = ((const float4*)pb_b)[a];                               \
        float c = ciou_pair(x1, y1, x2, y2, atan_t, bb.x, bb.y, bb.z, bb.w, \
                            atan_wh(bb.x, bb.y, bb.z, bb.w));               \
        float io = fminf(fmaxf(c, 0.f), 1.f);                               \
        float i2 = io * io;                                                 \
        float i6 = i2 * i2 * i2;                                            \
        int slot = atomicAdd(&s_n, 1);                                      \
        if (slot < CAP) { s_i6[slot] = i6; s_idx[slot] = a; }               \
      }                                                                     \
    }                                                                       \
  }
  LEVEL_LOOP(8, 80, 0)
  LEVEL_LOOP(16, 40, 6400)
  LEVEL_LOOP(32, 20, 8000)
#undef LEVEL_LOOP
  __syncthreads();
  int n = s_n; if (n > CAP) n = CAP;

  // Phase 2: top-10 by (i6 desc, anchor asc) — register/wave selection.
  {
    float v0 = -1.f, v1 = -1.f, v2 = -1.f, v3 = -1.f;
    int a0 = INT_MAX, a1 = INT_MAX, a2 = INT_MAX, a3 = INT_MAX;
    if (tid < n)       { v0 = s_i6[tid];       a0 = s_idx[tid]; }
    if (tid + 256 < n) { v1 = s_i6[tid + 256]; a1 = s_idx[tid + 256]; }
    if (tid + 512 < n) { v2 = s_i6[tid + 512]; a2 = s_idx[tid + 512]; }
    if (tid + 768 < n) { v3 = s_i6[tid + 768]; a3 = s_idx[tid + 768]; }
    for (int k = 0; k < KTOP; k++) {
      float bv = v0; int ba = a0;
      if (v1 > bv || (v1 == bv && a1 < ba)) { bv = v1; ba = a1; }
      if (v2 > bv || (v2 == bv && a2 < ba)) { bv = v2; ba = a2; }
      if (v3 > bv || (v3 == bv && a3 < ba)) { bv = v3; ba = a3; }
#pragma unroll
      for (int off = 32; off > 0; off >>= 1) {
        float ov = __shfl_xor(bv, off); int oa = __shfl_xor(ba, off);
        if (ov > bv || (ov == bv && oa < ba)) { bv = ov; ba = oa; }
      }
      if ((tid & 63) == 0) { xw_v[tid >> 6] = bv; xw_a[tid >> 6] = ba; }
      __syncthreads();
      float fv = xw_v[0]; int fa = xw_a[0];
      { float ov = xw_v[1]; int oa = xw_a[1];
        if (ov > fv || (ov == fv && oa < fa)) { fv = ov; fa = oa; } }
      { float ov = xw_v[2]; int oa = xw_a[2];
        if (ov > fv || (ov == fv && oa < fa)) { fv = ov; fa = oa; } }
      { float ov = xw_v[3]; int oa = xw_a[3];
        if (ov > fv || (ov == fv && oa < fa)) { fv = ov; fa = oa; } }
      if (tid == 0) { w_val[k] = fv; w_idx[k] = fa; }
      if (a0 == fa) { v0 = -1.f; a0 = INT_MAX; }
      if (a1 == fa) { v1 = -1.f; a1 = INT_MAX; }
      if (a2 == fa) { v2 = -1.f; a2 = INT_MAX; }
      if (a3 == fa) { v3 = -1.f; a3 = INT_MAX; }
      __syncthreads();
    }
  }

  // Phase 2b: evaluate tm of the 10 i6-winners; thr = min (or -1 if n<10).
  if (tid == 0) {
    float thr;
    if (n < KTOP) {
      thr = -1.f;                       // few candidates: evaluate all
    } else {
      thr = 3.402823466e+38f;           // FLT_MAX
      for (int k = 0; k < KTOP; k++) {
        int a = w_idx[k];
        float sc = pc_b[(size_t)a * NC + tc];
        float sig = 1.f / (1.f + expf(-sc));
        float tm = w_val[k] * sqrtf(sig);
        thr = fminf(thr, tm);
      }
    }
    s_thr = thr;
  }
  __syncthreads();
  float thr = s_thr;

  // Phase 3: sparse cls eval — only candidates with i6 >= thr.
  for (int e = tid; e < n; e += 256) {
    float i6 = s_i6[e];
    if (i6 >= thr) {
      int a = s_idx[e];
      float sc = pc_b[(size_t)a * NC + tc];
      float sig = 1.f / (1.f + expf(-sc));
      s_tm[e] = i6 * sqrtf(sig);
    } else {
      s_tm[e] = -1.f;                   // provably outside top-10
    }
  }
  __syncthreads();

  // Phase 4: top-10 by (tm desc, anchor asc) — same selection machinery.
  {
    float v0 = -1.f, v1 = -1.f, v2 = -1.f, v3 = -1.f;
    int a0 = INT_MAX, a1 = INT_MAX, a2 = INT_MAX, a3 = INT_MAX;
    if (tid < n)       { v0 = s_tm[tid];       a0 = s_idx[tid]; }
    if (tid + 256 < n) { v1 = s_tm[tid + 256]; a1 = s_idx[tid + 256]; }
    if (tid + 512 < n) { v2 = s_tm[tid + 512]; a2 = s_idx[tid + 512]; }
    if (tid + 768 < n) { v3 = s_tm[tid + 768]; a3 = s_idx[tid + 768]; }
    for (int k = 0; k < KTOP; k++) {
      float bv = v0; int ba = a0;
      if (v1 > bv || (v1 == bv && a1 < ba)) { bv = v1; ba = a1; }
      if (v2 > bv || (v2 == bv && a2 < ba)) { bv = v2; ba = a2; }
      if (v3 > bv || (v3 == bv && a3 < ba)) { bv = v3; ba = a3; }
#pragma unroll
      for (int off = 32; off > 0; off >>= 1) {
        float ov = __shfl_xor(bv, off); int oa = __shfl_xor(ba, off);
        if (ov > bv || (ov == bv && oa < ba)) { bv = ov; ba = oa; }
      }
      if ((tid & 63) == 0) { xw_v[tid >> 6] = bv; xw_a[tid >> 6] = ba; }
      __syncthreads();
      float fv = xw_v[0]; int fa = xw_a[0];
      { float ov = xw_v[1]; int oa = xw_a[1];
        if (ov > fv || (ov == fv && oa < fa)) { fv = ov; fa = oa; } }
      { float ov = xw_v[2]; int oa = xw_a[2];
        if (ov > fv || (ov == fv && oa < fa)) { fv = ov; fa = oa; } }
      { float ov = xw_v[3]; int oa = xw_a[3];
        if (ov > fv || (ov == fv && oa < fa)) { fv = ov; fa = oa; } }
      if (tid == 0) { w_val[k] = fv; w_idx[k] = fa; }
      if (a0 == fa) { v0 = -1.f; a0 = INT_MAX; }
      if (a1 == fa) { v1 = -1.f; a1 = INT_MAX; }
      if (a2 == fa) { v2 = -1.f; a2 = INT_MAX; }
      if (a3 == fa) { v3 = -1.f; a3 = INT_MAX; }
      __syncthreads();
    }
  }

  // write winners; recompute clipped ciou for each (10 per block, trivial)
  if (tid < KTOP) {
    int k = tid;
    int ai = w_idx[k]; float v = w_val[k];
    float io = 0.f;
    if (ai != INT_MAX && v > 0.f) {
      float4 bb = ((const float4*)pb_b)[ai];
      float c = ciou_pair(x1, y1, x2, y2, atan_t, bb.x, bb.y, bb.z, bb.w,
                          atan_wh(bb.x, bb.y, bb.z, bb.w));
      io = fminf(fmaxf(c, 0.f), 1.f);
    } else { ai = -1; v = 0.f; }
    size_t o = (size_t)row * KTOP + k;
    top_val[o] = v; top_idx[o] = ai; top_iou[o] = io;
  }
}

// ---- K2: one wave per entry: dedup + resolve + per-entry loss terms ------
__global__ __launch_bounds__(256) void k_resolve(
    const float* __restrict__ target, const float* __restrict__ pcls,
    const float* __restrict__ pbox, const float* __restrict__ anchors,
    const float* __restrict__ top_val, const int* __restrict__ top_idx,
    const float* __restrict__ top_iou,
    float* __restrict__ as_tm, float* __restrict__ as_x,
    float* __restrict__ as_cio, int* __restrict__ as_u,
    unsigned* __restrict__ mtg, unsigned* __restrict__ mig)
{
  int gid = blockIdx.x * 256 + threadIdx.x;
  int entry = gid >> 6;            // one 64-lane wave per entry
  int lane = threadIdx.x & 63;
  int b = entry / NE;
  int el = entry - b * NE;

  const float* bv = top_val + (size_t)b * NE;
  const int* bix = top_idx + (size_t)b * NE;
  float v = bv[el];
  int a = bix[el];

  bool dead = (v <= 0.f);
  int cnt = 0, first = NE;
  if (!dead) {
    for (int s = lane; s < NE; s += 64) {
      float v2 = bv[s]; int a2 = bix[s];
      if (v2 > 0.f && a2 == a) { cnt++; if (s < first) first = s; }
    }
    for (int off = 32; off > 0; off >>= 1) {
      cnt += __shfl_xor(cnt, off);
      int of = __shfl_xor(first, off);
      first = of < first ? of : first;
    }
    if (first != el) dead = true;   // not the representative entry
  }
  if (dead) {
    if (lane == 0) { as_tm[entry] = 0.f; as_x[entry] = 0.f;
                     as_cio[entry] = 0.f; as_u[entry] = 0; }
    return;
  }

  const float* pb = pbox + ((size_t)b * NA + a) * 4;
  int u; float tm = -1.f, io;
  if (cnt == 1) {
    u = el / KTOP; tm = v; io = top_iou[entry];
  } else {
    // duplicate: argmax over the 64 targets of clipped ciou, one per lane
    const float* tg = target + (size_t)(b * NT + lane) * 5;
    float tx1 = tg[1], ty1 = tg[2], tx2 = tg[3], ty2 = tg[4];
    float ta = atan_wh(tx1, ty1, tx2, ty2);
    float bx1 = pb[0], by1 = pb[1], bx2 = pb[2], by2 = pb[3];
    float pa = atan_wh(bx1, by1, bx2, by2);
    float c = ciou_pair(tx1, ty1, tx2, ty2, ta, bx1, by1, bx2, by2, pa);
    float cc = fminf(fmaxf(c, 0.f), 1.f);
    float best = cc; int bu = lane;
    for (int off = 32; off > 0; off >>= 1) {
      float ob = __shfl_xor(best, off);
      int ou = __shfl_xor(bu, off);
      if (ob > best || (ob == best && ou < bu)) { best = ob; bu = ou; }
    }
    u = bu; io = best;               // lowest-t tie-break == jnp.argmax
  }

  if (lane == 0) {
    const float* tgu = target + (size_t)(b * NT + u) * 5;
    float ux1 = tgu[1], uy1 = tgu[2], ux2 = tgu[3], uy2 = tgu[4];
    int cu = (int)tgu[0]; cu = cu < 0 ? 0 : (cu > NC - 1 ? NC - 1 : cu);
    float x = pcls[((size_t)b * NA + a) * NC + cu];
    if (cnt != 1) {
      float2 an = ((const float2*)anchors)[a];
      float gm = (ux1 < an.x && an.x < ux2 && uy1 < an.y && an.y < uy2) ? 1.f : 0.f;
      float i2 = io * io; float i6 = i2 * i2 * i2;
      float sig = 1.f / (1.f + expf(-x));
      tm = gm * i6 * sqrtf(sig);
    }
    float bx1 = pb[0], by1 = pb[1], bx2 = pb[2], by2 = pb[3];
    float c = ciou_pair(ux1, uy1, ux2, uy2, atan_wh(ux1, uy1, ux2, uy2),
                        bx1, by1, bx2, by2, atan_wh(bx1, by1, bx2, by2));
    as_tm[entry] = tm; as_x[entry] = x; as_cio[entry] = 1.f - c; as_u[entry] = u;
    atomicMax(&mtg[b * NT + u], __float_as_uint(tm));  // non-neg: uint order == float order
    atomicMax(&mig[b * NT + u], __float_as_uint(io));
  }
}

// ---- K3: fused softplus sums + per-batch sums ----------------------------
__global__ __launch_bounds__(256) void k_bce_sums(
    const float* __restrict__ pcls,
    const float* __restrict__ as_tm, const float* __restrict__ as_x,
    const float* __restrict__ as_cio, const int* __restrict__ as_u,
    const unsigned* __restrict__ mtg, const unsigned* __restrict__ mig,
    double* __restrict__ bce_part, double* __restrict__ k2_part)
{
  int tid = threadIdx.x;
  __shared__ double red[256];

  if (blockIdx.x < BCE_BLOCKS) {
    const float4* p4 = (const float4*)pcls;
    const int n4 = NB * NA * NC / 4;  // 5,376,000
    double acc = 0.0;
    for (int i = blockIdx.x * 256 + tid; i < n4; i += BCE_BLOCKS * 256) {
      float4 v = p4[i];
      float p = (softplus_fast(v.x) + softplus_fast(v.y)) +
                (softplus_fast(v.z) + softplus_fast(v.w));
      acc += (double)p;
    }
    red[tid] = acc; __syncthreads();
    for (int off = 128; off > 0; off >>= 1) {
      if (tid < off) red[tid] += red[tid + off];
      __syncthreads();
    }
    if (tid == 0) bce_part[blockIdx.x] = red[0];
    return;
  }

  int b = blockIdx.x - BCE_BLOCKS;
  double s1 = 0.0, s2 = 0.0, s3 = 0.0;
  for (int e = tid; e < NE; e += 256) {
    size_t o = (size_t)b * NE + e;
    float tm = as_tm[o];
    int u = as_u[o];
    float maxt = __uint_as_float(mtg[b * NT + u]);
    float maxi = __uint_as_float(mig[b * NT + u]);
    float nrm = tm / (maxt + 1e-9f) * maxi;   // exact 0 for dead entries
    s1 += (double)nrm;
    s2 += (double)as_x[o] * (double)nrm;
    s3 += (double)(as_cio[o] * nrm);
  }
  red[tid] = s1; __syncthreads();
  for (int off = 128; off > 0; off >>= 1) {
    if (tid < off) red[tid] += red[tid + off];
    __syncthreads();
  }
  if (tid == 0) k2_part[b * 3 + 0] = red[0];
  __syncthreads();
  red[tid] = s2; __syncthreads();
  for (int off = 128; off > 0; off >>= 1) {
    if (tid < off) red[tid] += red[tid + off];
    __syncthreads();
  }
  if (tid == 0) k2_part[b * 3 + 1] = red[0];
  __syncthreads();
  red[tid] = s3; __syncthreads();
  for (int off = 128; off > 0; off >>= 1) {
    if (tid < off) red[tid] += red[tid + off];
    __syncthreads();
  }
  if (tid == 0) k2_part[b * 3 + 2] = red[0];
}

// ---- K4: combine everything ----------------------------------------------
__global__ __launch_bounds__(256) void k_final(const double* __restrict__ bce_part,
                                               const double* __restrict__ k2_part,
                                               float* __restrict__ out) {
  __shared__ double red[256];
  int tid = threadIdx.x;
  double s = 0.0;
  for (int i = tid; i < BCE_BLOCKS; i += 256) s += bce_part[i];
  red[tid] = s; __syncthreads();
  for (int off = 128; off > 0; off >>= 1) {
    if (tid < off) red[tid] += red[tid + off];
    __syncthreads();
  }
  double s4 = red[0]; __syncthreads();

  red[tid] = (tid < NB) ? k2_part[3 * tid + 0] : 0.0; __syncthreads();
  for (int off = 128; off > 0; off >>= 1) {
    if (tid < off) red[tid] += red[tid + off];
    __syncthreads();
  }
  double s1 = red[0]; __syncthreads();

  red[tid] = (tid < NB) ? k2_part[3 * tid + 1] : 0.0; __syncthreads();
  for (int off = 128; off > 0; off >>= 1) {
    if (tid < off) red[tid] += red[tid + off];
    __syncthreads();
  }
  double s2 = red[0]; __syncthreads();

  red[tid] = (tid < NB) ? k2_part[3 * tid + 2] : 0.0; __syncthreads();
  for (int off = 128; off > 0; off >>= 1) {
    if (tid < off) red[tid] += red[tid + off];
    __syncthreads();
  }
  double s3 = red[0];

  if (tid == 0) {
    double cn = fmax(s1, 1.0);
    out[0] = (float)(s3 / cn);         // loss_iou
    out[1] = (float)((s4 - s2) / cn);  // loss_cls
  }
}

extern "C" void kernel_launch(void* const* d_in, const int* in_sizes, int n_in,
                              void* d_out, int out_size, void* d_ws, size_t ws_size,
                              hipStream_t stream) {
  const float* target  = (const float*)d_in[0];  // [32,64,5]
  const float* pcls    = (const float*)d_in[1];  // [32,8400,80]
  const float* pbox    = (const float*)d_in[2];  // [32,8400,4]
  const float* anchors = (const float*)d_in[3];  // [8400,2]
  float* out = (float*)d_out;

  char* ws = (char*)d_ws;
  float*    top_val = (float*)ws;                    // 20480 f  =  81,920 B
  int*      top_idx = (int*)(ws + 81920);            //             81,920 B
  float*    top_iou = (float*)(ws + 163840);         //             81,920 B
  float*    as_tm   = (float*)(ws + 245760);         //             81,920 B
  float*    as_x    = (float*)(ws + 327680);         //             81,920 B
  float*    as_cio  = (float*)(ws + 409600);         //             81,920 B
  int*      as_u    = (int*)(ws + 491520);           //             81,920 B
  unsigned* mtg     = (unsigned*)(ws + 573440);      // 2048 u   =   8,192 B
  unsigned* mig     = (unsigned*)(ws + 581632);      //              8,192 B
  double*   k2_part = (double*)(ws + 589824);        // 96 d     =     768 B
  double*   k3_part = (double*)(ws + 590592);        // 2048 d   =  16,384 B
  // total ws use: 606,976 B

  k_topk<<<NB * NT, 256, 0, stream>>>(target, pcls, pbox,
                                      top_val, top_idx, top_iou, mtg, mig);
  k_resolve<<<(NB * NE * 64) / 256, 256, 0, stream>>>(
      target, pcls, pbox, anchors, top_val, top_idx, top_iou,
      as_tm, as_x, as_cio, as_u, mtg, mig);
  k_bce_sums<<<BCE_BLOCKS + NB, 256, 0, stream>>>(
      pcls, as_tm, as_x, as_cio, as_u, mtg, mig, k3_part, k2_part);
  k_final<<<1, 256, 0, stream>>>(k3_part, k2_part, out);
}

// Round 17
// 78.019 us; speedup vs baseline: 1.2545x; 1.2545x over previous
//
#include <hip/hip_runtime.h>
#include <climits>
#include <cmath>

// YOLOv9 loss forward.  B=32 T=64 A=8400 C=80.
// r8 structure + u64 packed-key top-10 (halves selection instrs) +
// 4-entries-per-wave resolve (quarters dedup-scan traffic).
//   K1 k_topk     : analytic enum + u64-key block top-10
//   K2 k_resolve  : 4 candidate entries per wave
//   K3 k_bce_sums : blocks [0,2048) softplus sums; [2048,2080) batch sums
//   K4 k_final    : combine -> out

#define NB 32
#define NT 64
#define NA 8400
#define NC 80
#define KTOP 10
#define NE (NT * KTOP)   // 640 entries per batch
#define CAP 1024
#define EPSF 1e-7f
#define INV_PI2 0.40528473456935108577f  // 4/pi^2
#define LOG2E_F 1.44269504088896340736f
#define LN2_F   0.69314718055994530942f
#define BCE_BLOCKS 2048

typedef unsigned long long u64;

__device__ __forceinline__ float atan_wh(float x1, float y1, float x2, float y2) {
  return atanf((x2 - x1) / (y2 - y1 + EPSF));
}

__device__ __forceinline__ float ciou_pair(
    float ax1, float ay1, float ax2, float ay2, float atA,
    float bx1, float by1, float bx2, float by2, float atB)
{
  float xi1 = fmaxf(ax1, bx1), yi1 = fmaxf(ay1, by1);
  float xi2 = fminf(ax2, bx2), yi2 = fminf(ay2, by2);
  float inter = fmaxf(xi2 - xi1, 0.f) * fmaxf(yi2 - yi1, 0.f);
  float a1 = (ax2 - ax1) * (ay2 - ay1);
  float a2 = (bx2 - bx1) * (by2 - by1);
  float iou = inter / (a1 + a2 - inter + EPSF);
  float dcx = (ax2 + ax1) * 0.5f - (bx2 + bx1) * 0.5f;
  float dcy = (ay2 + ay1) * 0.5f - (by2 + by1) * 0.5f;
  float cent = dcx * dcx + dcy * dcy;
  float cw = fmaxf(ax2, bx2) - fminf(ax1, bx1);
  float ch = fmaxf(ay2, by2) - fminf(ay1, by1);
  float diag = cw * cw + ch * ch + EPSF;
  float dv = atA - atB;
  float v = INV_PI2 * dv * dv;
  float alpha = v / (v - iou + 1.f + EPSF);
  return iou - cent / diag - alpha * v;
}

// Fast softplus on the native transcendental pipe (verified r7-r16).
__device__ __forceinline__ float softplus_fast(float x) {
  float e = exp2f(-LOG2E_F * fabsf(x));     // v_exp_f32
  float l = __log2f(1.f + e);               // v_log_f32
  return fmaxf(x, 0.f) + LN2_F * l;
}

__device__ __forceinline__ float sigmoid_fast(float x) {
  return 1.f / (1.f + exp2f(-LOG2E_F * x)); // single v_exp_f32
}

// key = (bits(tm) << 32) | (INT_MAX - a).  tm >= 0 so float bits are
// order-monotone; bigger key == (tm desc, anchor asc) == lax.top_k order.
// Sentinel 0 < every real key (real: low32 = INT_MAX-a > 0 since a < 2^31).
__device__ __forceinline__ u64 pack_key(float tm, int a) {
  return ((u64)__float_as_uint(tm) << 32) | (unsigned)(INT_MAX - a);
}

// ---- K1: per (b,t) row: analytic enum + u64-key block top-10 -------------
// Anchors are 3 meshgrids: level l has n_l x n_l cells at (i+0.5)*s_l,
// s = {8,16,32}, n = {80,40,20}, base = {0,6400,8000}; a = base + iy*n + ix.
__global__ __launch_bounds__(256) void k_topk(
    const float* __restrict__ target,   // [B,T,5]
    const float* __restrict__ pcls,     // [B,A,C]
    const float* __restrict__ pbox,     // [B,A,4]
    float* __restrict__ top_val, int* __restrict__ top_idx,
    float* __restrict__ top_iou,
    unsigned* __restrict__ mtg, unsigned* __restrict__ mig)
{
  int row = blockIdx.x;            // b*NT + t   (grid is exactly NB*NT)
  int tid = threadIdx.x;
  if (tid == 0) { mtg[row] = 0u; mig[row] = 0u; }  // zero max tables
  int b = row >> 6;
  const float* tg = target + (size_t)row * 5;
  float tcf = tg[0];
  float x1 = tg[1], y1 = tg[2], x2 = tg[3], y2 = tg[4];
  int tc = (int)tcf; tc = tc < 0 ? 0 : (tc > NC - 1 ? NC - 1 : tc);
  float atan_t = atan_wh(x1, y1, x2, y2);

  __shared__ int s_n;
  __shared__ u64 s_key[CAP];       // 8 KB
  __shared__ u64 xw_k[4];
  __shared__ u64 w_key[KTOP];
  if (tid == 0) s_n = 0;
  __syncthreads();

  const float* pb_b = pbox + (size_t)b * NA * 4;
  const float* pc_b = pcls + (size_t)b * NA * NC;

#define LEVEL_LOOP(S, N, BASE)                                              \
  {                                                                         \
    const float s = (float)(S);                                             \
    int ix0 = (int)floorf(x1 / s - 0.5f); if (ix0 < 0) ix0 = 0;             \
    int ix1 = (int)ceilf (x2 / s - 0.5f); if (ix1 > (N)-1) ix1 = (N)-1;     \
    int iy0 = (int)floorf(y1 / s - 0.5f); if (iy0 < 0) iy0 = 0;             \
    int iy1 = (int)ceilf (y2 / s - 0.5f); if (iy1 > (N)-1) iy1 = (N)-1;     \
    int w = ix1 - ix0 + 1; w = w < 0 ? 0 : w;                               \
    int h = iy1 - iy0 + 1; h = h < 0 ? 0 : h;                               \
    int cnt = w * h;                                                        \
    for (int k = tid; k < cnt; k += 256) {                                  \
      int ix = ix0 + k % w;                                                 \
      int iy = iy0 + k / w;                                                 \
      float anx = (ix + 0.5f) * s;                                          \
      float any_ = (iy + 0.5f) * s;                                         \
      if (x1 < anx && anx < x2 && y1 < any_ && any_ < y2) {                 \
        int a = (BASE) + iy * (N) + ix;                                     \
        float4 bb = ((const float4*)pb_b)[a];                               \
        float c = ciou_pair(x1, y1, x2, y2, atan_t, bb.x, bb.y, bb.z, bb.w, \
                            atan_wh(bb.x, bb.y, bb.z, bb.w));               \
        float io = fminf(fmaxf(c, 0.f), 1.f);                               \
        float i2 = io * io;                                                 \
        float i6 = i2 * i2 * i2;                                            \
        float sc = pc_b[(size_t)a * NC + tc];                               \
        float tm = i6 * sqrtf(sigmoid_fast(sc));                            \
        int slot = atomicAdd(&s_n, 1);                                      \
        if (slot < CAP) s_key[slot] = pack_key(tm, a);                      \
      }                                                                     \
    }                                                                       \
  }
  LEVEL_LOOP(8, 80, 0)
  LEVEL_LOOP(16, 40, 6400)
  LEVEL_LOOP(32, 20, 8000)
#undef LEVEL_LOOP
  __syncthreads();
  int n = s_n; if (n > CAP) n = CAP;

  // candidates in 4 static u64 register slots per thread
  u64 k0 = 0, k1 = 0, k2 = 0, k3 = 0;
  if (tid < n)       k0 = s_key[tid];
  if (tid + 256 < n) k1 = s_key[tid + 256];
  if (tid + 512 < n) k2 = s_key[tid + 512];
  if (tid + 768 < n) k3 = s_key[tid + 768];

  // 10 rounds: local 4-max -> wave butterfly -> 4-wave LDS merge -> kill.
  // Single u64 compare everywhere == (tm desc, anchor asc).
  for (int k = 0; k < KTOP; k++) {
    u64 bk = k0;
    if (k1 > bk) bk = k1;
    if (k2 > bk) bk = k2;
    if (k3 > bk) bk = k3;
#pragma unroll
    for (int off = 32; off > 0; off >>= 1) {
      u64 ok = __shfl_xor(bk, off);
      if (ok > bk) bk = ok;
    }
    if ((tid & 63) == 0) xw_k[tid >> 6] = bk;
    __syncthreads();
    u64 fk = xw_k[0];
    if (xw_k[1] > fk) fk = xw_k[1];
    if (xw_k[2] > fk) fk = xw_k[2];
    if (xw_k[3] > fk) fk = xw_k[3];
    if (tid == 0) w_key[k] = fk;
    // kill winner (keys unique per anchor; sentinel fk==0 kills nothing real)
    if (fk != 0) {
      if (k0 == fk) k0 = 0;
      if (k1 == fk) k1 = 0;
      if (k2 == fk) k2 = 0;
      if (k3 == fk) k3 = 0;
    }
    __syncthreads();
  }

  // write winners; recompute clipped ciou for each (10 per block, trivial)
  if (tid < KTOP) {
    int k = tid;
    u64 key = w_key[k];
    float v = __uint_as_float((unsigned)(key >> 32));
    int ai = INT_MAX - (int)(key & 0xFFFFFFFFu);
    float io = 0.f;
    if (key != 0 && v > 0.f) {
      float4 bb = ((const float4*)pb_b)[ai];
      float c = ciou_pair(x1, y1, x2, y2, atan_t, bb.x, bb.y, bb.z, bb.w,
                          atan_wh(bb.x, bb.y, bb.z, bb.w));
      io = fminf(fmaxf(c, 0.f), 1.f);
    } else { ai = -1; v = 0.f; }
    size_t o = (size_t)row * KTOP + k;
    top_val[o] = v; top_idx[o] = ai; top_iou[o] = io;
  }
}

// ---- K2: 4 entries per wave: shared dedup scan + per-entry loss terms ----
__global__ __launch_bounds__(256) void k_resolve(
    const float* __restrict__ target, const float* __restrict__ pcls,
    const float* __restrict__ pbox, const float* __restrict__ anchors,
    const float* __restrict__ top_val, const int* __restrict__ top_idx,
    const float* __restrict__ top_iou,
    float* __restrict__ as_tm, float* __restrict__ as_x,
    float* __restrict__ as_cio, int* __restrict__ as_u,
    unsigned* __restrict__ mtg, unsigned* __restrict__ mig)
{
  int wave = (blockIdx.x * 256 + threadIdx.x) >> 6;  // 0..5119
  int lane = threadIdx.x & 63;
  int e0 = wave * 4;               // 4 consecutive entries; NE%4==0 -> same b
  int b = e0 / NE;

  const float* bv = top_val + (size_t)b * NE;
  const int* bix = top_idx + (size_t)b * NE;

  int ea[4]; float ev[4];
  bool dead[4];
  int cnt[4]; int first[4];
#pragma unroll
  for (int j = 0; j < 4; j++) {
    int el = (e0 - b * NE) + j;
    ev[j] = bv[el]; ea[j] = bix[el];
    dead[j] = (ev[j] <= 0.f);
    cnt[j] = 0; first[j] = NE;
  }

  // single shared scan of this batch's 640 entries, tested against 4 anchors
  for (int s = lane; s < NE; s += 64) {
    float v2 = bv[s]; int a2 = bix[s];
    bool live = (v2 > 0.f);
#pragma unroll
    for (int j = 0; j < 4; j++) {
      if (live && a2 == ea[j]) { cnt[j]++; if (s < first[j]) first[j] = s; }
    }
  }
#pragma unroll
  for (int j = 0; j < 4; j++) {
    for (int off = 32; off > 0; off >>= 1) {
      cnt[j] += __shfl_xor(cnt[j], off);
      int of = __shfl_xor(first[j], off);
      first[j] = of < first[j] ? of : first[j];
    }
  }

#pragma unroll
  for (int j = 0; j < 4; j++) {
    int entry = e0 + j;
    int el = (e0 - b * NE) + j;
    if (!dead[j] && first[j] != el) dead[j] = true;  // not representative
    if (dead[j]) {
      if (lane == 0) { as_tm[entry] = 0.f; as_x[entry] = 0.f;
                       as_cio[entry] = 0.f; as_u[entry] = 0; }
      continue;
    }
    int a = ea[j];
    const float* pb = pbox + ((size_t)b * NA + a) * 4;
    int u; float tm = -1.f, io;
    if (cnt[j] == 1) {
      u = el / KTOP; tm = ev[j]; io = top_iou[entry];
    } else {
      // duplicate: argmax over 64 targets of clipped ciou, one per lane
      const float* tg = target + (size_t)(b * NT + lane) * 5;
      float tx1 = tg[1], ty1 = tg[2], tx2 = tg[3], ty2 = tg[4];
      float ta = atan_wh(tx1, ty1, tx2, ty2);
      float bx1 = pb[0], by1 = pb[1], bx2 = pb[2], by2 = pb[3];
      float pa = atan_wh(bx1, by1, bx2, by2);
      float c = ciou_pair(tx1, ty1, tx2, ty2, ta, bx1, by1, bx2, by2, pa);
      float cc = fminf(fmaxf(c, 0.f), 1.f);
      float best = cc; int bu = lane;
      for (int off = 32; off > 0; off >>= 1) {
        float ob = __shfl_xor(best, off);
        int ou = __shfl_xor(bu, off);
        if (ob > best || (ob == best && ou < bu)) { best = ob; bu = ou; }
      }
      u = bu; io = best;             // lowest-t tie-break == jnp.argmax
    }

    if (lane == 0) {
      const float* tgu = target + (size_t)(b * NT + u) * 5;
      float ux1 = tgu[1], uy1 = tgu[2], ux2 = tgu[3], uy2 = tgu[4];
      int cu = (int)tgu[0]; cu = cu < 0 ? 0 : (cu > NC - 1 ? NC - 1 : cu);
      float x = pcls[((size_t)b * NA + a) * NC + cu];
      if (cnt[j] != 1) {
        float2 an = ((const float2*)anchors)[a];
        float gm = (ux1 < an.x && an.x < ux2 && uy1 < an.y && an.y < uy2)
                       ? 1.f : 0.f;
        float i2 = io * io; float i6 = i2 * i2 * i2;
        float sig = sigmoid_fast(x);
        tm = gm * i6 * sqrtf(sig);
      }
      float bx1 = pb[0], by1 = pb[1], bx2 = pb[2], by2 = pb[3];
      float c = ciou_pair(ux1, uy1, ux2, uy2, atan_wh(ux1, uy1, ux2, uy2),
                          bx1, by1, bx2, by2, atan_wh(bx1, by1, bx2, by2));
      as_tm[entry] = tm; as_x[entry] = x; as_cio[entry] = 1.f - c; as_u[entry] = u;
      atomicMax(&mtg[b * NT + u], __float_as_uint(tm));  // non-neg floats
      atomicMax(&mig[b * NT + u], __float_as_uint(io));
    }
  }
}

// ---- K3: fused softplus sums + per-batch sums ----------------------------
__global__ __launch_bounds__(256) void k_bce_sums(
    const float* __restrict__ pcls,
    const float* __restrict__ as_tm, const float* __restrict__ as_x,
    const float* __restrict__ as_cio, const int* __restrict__ as_u,
    const unsigned* __restrict__ mtg, const unsigned* __restrict__ mig,
    double* __restrict__ bce_part, double* __restrict__ k2_part)
{
  int tid = threadIdx.x;
  __shared__ double red[256];

  if (blockIdx.x < BCE_BLOCKS) {
    const float4* p4 = (const float4*)pcls;
    const int n4 = NB * NA * NC / 4;  // 5,376,000
    double acc = 0.0;
    for (int i = blockIdx.x * 256 + tid; i < n4; i += BCE_BLOCKS * 256) {
      float4 v = p4[i];
      float p = (softplus_fast(v.x) + softplus_fast(v.y)) +
                (softplus_fast(v.z) + softplus_fast(v.w));
      acc += (double)p;
    }
    red[tid] = acc; __syncthreads();
    for (int off = 128; off > 0; off >>= 1) {
      if (tid < off) red[tid] += red[tid + off];
      __syncthreads();
    }
    if (tid == 0) bce_part[blockIdx.x] = red[0];
    return;
  }

  int b = blockIdx.x - BCE_BLOCKS;
  double s1 = 0.0, s2 = 0.0, s3 = 0.0;
  for (int e = tid; e < NE; e += 256) {
    size_t o = (size_t)b * NE + e;
    float tm = as_tm[o];
    int u = as_u[o];
    float maxt = __uint_as_float(mtg[b * NT + u]);
    float maxi = __uint_as_float(mig[b * NT + u]);
    float nrm = tm / (maxt + 1e-9f) * maxi;   // exact 0 for dead entries
    s1 += (double)nrm;
    s2 += (double)as_x[o] * (double)nrm;
    s3 += (double)(as_cio[o] * nrm);
  }
  red[tid] = s1; __syncthreads();
  for (int off = 128; off > 0; off >>= 1) {
    if (tid < off) red[tid] += red[tid + off];
    __syncthreads();
  }
  if (tid == 0) k2_part[b * 3 + 0] = red[0];
  __syncthreads();
  red[tid] = s2; __syncthreads();
  for (int off = 128; off > 0; off >>= 1) {
    if (tid < off) red[tid] += red[tid + off];
    __syncthreads();
  }
  if (tid == 0) k2_part[b * 3 + 1] = red[0];
  __syncthreads();
  red[tid] = s3; __syncthreads();
  for (int off = 128; off > 0; off >>= 1) {
    if (tid < off) red[tid] += red[tid + off];
    __syncthreads();
  }
  if (tid == 0) k2_part[b * 3 + 2] = red[0];
}

// ---- K4: combine everything ----------------------------------------------
__global__ __launch_bounds__(256) void k_final(const double* __restrict__ bce_part,
                                               const double* __restrict__ k2_part,
                                               float* __restrict__ out) {
  __shared__ double red[256];
  int tid = threadIdx.x;
  double s = 0.0;
  for (int i = tid; i < BCE_BLOCKS; i += 256) s += bce_part[i];
  red[tid] = s; __syncthreads();
  for (int off = 128; off > 0; off >>= 1) {
    if (tid < off) red[tid] += red[tid + off];
    __syncthreads();
  }
  double s4 = red[0]; __syncthreads();

  red[tid] = (tid < NB) ? k2_part[3 * tid + 0] : 0.0; __syncthreads();
  for (int off = 128; off > 0; off >>= 1) {
    if (tid < off) red[tid] += red[tid + off];
    __syncthreads();
  }
  double s1 = red[0]; __syncthreads();

  red[tid] = (tid < NB) ? k2_part[3 * tid + 1] : 0.0; __syncthreads();
  for (int off = 128; off > 0; off >>= 1) {
    if (tid < off) red[tid] += red[tid + off];
    __syncthreads();
  }
  double s2 = red[0]; __syncthreads();

  red[tid] = (tid < NB) ? k2_part[3 * tid + 2] : 0.0; __syncthreads();
  for (int off = 128; off > 0; off >>= 1) {
    if (tid < off) red[tid] += red[tid + off];
    __syncthreads();
  }
  double s3 = red[0];

  if (tid == 0) {
    double cn = fmax(s1, 1.0);
    out[0] = (float)(s3 / cn);         // loss_iou
    out[1] = (float)((s4 - s2) / cn);  // loss_cls
  }
}

extern "C" void kernel_launch(void* const* d_in, const int* in_sizes, int n_in,
                              void* d_out, int out_size, void* d_ws, size_t ws_size,
                              hipStream_t stream) {
  const float* target  = (const float*)d_in[0];  // [32,64,5]
  const float* pcls    = (const float*)d_in[1];  // [32,8400,80]
  const float* pbox    = (const float*)d_in[2];  // [32,8400,4]
  const float* anchors = (const float*)d_in[3];  // [8400,2]
  float* out = (float*)d_out;

  char* ws = (char*)d_ws;
  float*    top_val = (float*)ws;                    // 20480 f  =  81,920 B
  int*      top_idx = (int*)(ws + 81920);            //             81,920 B
  float*    top_iou = (float*)(ws + 163840);         //             81,920 B
  float*    as_tm   = (float*)(ws + 245760);         //             81,920 B
  float*    as_x    = (float*)(ws + 327680);         //             81,920 B
  float*    as_cio  = (float*)(ws + 409600);         //             81,920 B
  int*      as_u    = (int*)(ws + 491520);           //             81,920 B
  unsigned* mtg     = (unsigned*)(ws + 573440);      // 2048 u   =   8,192 B
  unsigned* mig     = (unsigned*)(ws + 581632);      //              8,192 B
  double*   k2_part = (double*)(ws + 589824);        // 96 d     =     768 B
  double*   k3_part = (double*)(ws + 590592);        // 2048 d   =  16,384 B
  // total ws use: 606,976 B

  k_topk<<<NB * NT, 256, 0, stream>>>(target, pcls, pbox,
                                      top_val, top_idx, top_iou, mtg, mig);
  k_resolve<<<(NB * NE / 4 * 64) / 256, 256, 0, stream>>>(
      target, pcls, pbox, anchors, top_val, top_idx, top_iou,
      as_tm, as_x, as_cio, as_u, mtg, mig);
  k_bce_sums<<<BCE_BLOCKS + NB, 256, 0, stream>>>(
      pcls, as_tm, as_x, as_cio, as_u, mtg, mig, k3_part, k2_part);
  k_final<<<1, 256, 0, stream>>>(k3_part, k2_part, out);
}

// Round 20
// 65.978 us; speedup vs baseline: 1.4834x; 1.1825x over previous
//
#include <hip/hip_runtime.h>
#include <climits>
#include <cmath>

// YOLOv9 loss forward.  B=32 T=64 A=8400 C=80.
// r17 champion + k_topk: ONE WAVE PER ROW, private LDS segment, u64-key
// register top-10, zero block barriers.  r18's crash root cause fixed:
// enum loop is now UNIFORM-TRIP (k0 += 64, all lanes in, pred-guarded) so
// nmine is wave-uniform and every key slot < n is initialized.
//   K1 k_topk     : 512 blocks x 4 waves; wave w owns row bid*4+w
//   K2 k_resolve  : 4 candidate entries per wave
//   K3 k_bce_sums : blocks [0,2048) softplus sums; [2048,2080) batch sums
//   K4 k_final    : combine -> out

#define NB 32
#define NT 64
#define NA 8400
#define NC 80
#define KTOP 10
#define NE (NT * KTOP)   // 640 entries per batch
#define CAPW 768         // per-wave candidate cap (worst case 722)
#define EPSF 1e-7f
#define INV_PI2 0.40528473456935108577f  // 4/pi^2
#define LOG2E_F 1.44269504088896340736f
#define LN2_F   0.69314718055994530942f
#define BCE_BLOCKS 2048

typedef unsigned long long u64;

__device__ __forceinline__ float atan_wh(float x1, float y1, float x2, float y2) {
  return atanf((x2 - x1) / (y2 - y1 + EPSF));
}

__device__ __forceinline__ float ciou_pair(
    float ax1, float ay1, float ax2, float ay2, float atA,
    float bx1, float by1, float bx2, float by2, float atB)
{
  float xi1 = fmaxf(ax1, bx1), yi1 = fmaxf(ay1, by1);
  float xi2 = fminf(ax2, bx2), yi2 = fminf(ay2, by2);
  float inter = fmaxf(xi2 - xi1, 0.f) * fmaxf(yi2 - yi1, 0.f);
  float a1 = (ax2 - ax1) * (ay2 - ay1);
  float a2 = (bx2 - bx1) * (by2 - by1);
  float iou = inter / (a1 + a2 - inter + EPSF);
  float dcx = (ax2 + ax1) * 0.5f - (bx2 + bx1) * 0.5f;
  float dcy = (ay2 + ay1) * 0.5f - (by2 + by1) * 0.5f;
  float cent = dcx * dcx + dcy * dcy;
  float cw = fmaxf(ax2, bx2) - fminf(ax1, bx1);
  float ch = fmaxf(ay2, by2) - fminf(ay1, by1);
  float diag = cw * cw + ch * ch + EPSF;
  float dv = atA - atB;
  float v = INV_PI2 * dv * dv;
  float alpha = v / (v - iou + 1.f + EPSF);
  return iou - cent / diag - alpha * v;
}

// Fast softplus on the native transcendental pipe (verified r7-r17).
__device__ __forceinline__ float softplus_fast(float x) {
  float e = exp2f(-LOG2E_F * fabsf(x));     // v_exp_f32
  float l = __log2f(1.f + e);               // v_log_f32
  return fmaxf(x, 0.f) + LN2_F * l;
}

__device__ __forceinline__ float sigmoid_fast(float x) {
  return 1.f / (1.f + exp2f(-LOG2E_F * x)); // single v_exp_f32
}

// key = (bits(tm) << 32) | (INT_MAX - a); bigger == (tm desc, anchor asc).
// Real keys are > 0 (low32 = INT_MAX - a > 0); sentinel 0 below all real.
__device__ __forceinline__ u64 pack_key(float tm, int a) {
  return ((u64)__float_as_uint(tm) << 32) | (unsigned)(INT_MAX - a);
}

// ---- K1: one wave per row; barrier-free u64 top-10 -----------------------
// Anchors: 3 meshgrids, level l: n_l x n_l at (i+0.5)*s_l; s={8,16,32},
// n={80,40,20}, base={0,6400,8000}; a = base + iy*n + ix.
__global__ __launch_bounds__(256) void k_topk(
    const float* __restrict__ target,   // [B,T,5]
    const float* __restrict__ pcls,     // [B,A,C]
    const float* __restrict__ pbox,     // [B,A,4]
    float* __restrict__ top_val, int* __restrict__ top_idx,
    float* __restrict__ top_iou,
    unsigned* __restrict__ mtg, unsigned* __restrict__ mig)
{
  int wv = threadIdx.x >> 6;       // wave 0..3 in block
  int lane = threadIdx.x & 63;
  int row = blockIdx.x * 4 + wv;   // grid 512 blocks -> rows 0..2047
  if (lane == 0) { mtg[row] = 0u; mig[row] = 0u; }
  int b = row >> 6;
  const float* tg = target + (size_t)row * 5;
  float tcf = tg[0];
  float x1 = tg[1], y1 = tg[2], x2 = tg[3], y2 = tg[4];
  int tc = (int)tcf; tc = tc < 0 ? 0 : (tc > NC - 1 ? NC - 1 : tc);
  float atan_t = atan_wh(x1, y1, x2, y2);

  __shared__ u64 s_key[4][CAPW];   // private per-wave segments, 24.6 KB
  u64* my = s_key[wv];

  const float* pb_b = pbox + (size_t)b * NA * 4;
  const float* pc_b = pcls + (size_t)b * NA * NC;

  int nmine = 0;                   // wave-uniform (uniform-trip loop below)

  // UNIFORM-TRIP lane-strided enum: all 64 lanes iterate ceil(cnt/64) times;
  // bounds test folded into pred -> ballot is full-wave, nmine uniform.
#define LEVEL_LOOP(S, N, BASE)                                              \
  {                                                                         \
    const float s = (float)(S);                                             \
    int ix0 = (int)floorf(x1 / s - 0.5f); if (ix0 < 0) ix0 = 0;             \
    int ix1 = (int)ceilf (x2 / s - 0.5f); if (ix1 > (N)-1) ix1 = (N)-1;     \
    int iy0 = (int)floorf(y1 / s - 0.5f); if (iy0 < 0) iy0 = 0;             \
    int iy1 = (int)ceilf (y2 / s - 0.5f); if (iy1 > (N)-1) iy1 = (N)-1;     \
    int w = ix1 - ix0 + 1; w = w < 0 ? 0 : w;                               \
    int h = iy1 - iy0 + 1; h = h < 0 ? 0 : h;                               \
    int cnt = w * h;                                                        \
    unsigned magic = w > 0 ? (0xFFFFFFFFu / (unsigned)w) + 1u : 0u;         \
    for (int k0 = 0; k0 < cnt; k0 += 64) {                                  \
      int k = k0 + lane;                                                    \
      bool pred = false; u64 key = 0;                                       \
      if (k < cnt) {                                                        \
        int iy = (int)__umulhi((unsigned)k, magic);  /* exact k/w */        \
        int ix = k - iy * w;                                                \
        ix += ix0; iy += iy0;                                               \
        float anx = (ix + 0.5f) * s;                                        \
        float any_ = (iy + 0.5f) * s;                                       \
        pred = (x1 < anx && anx < x2 && y1 < any_ && any_ < y2);            \
        if (pred) {                                                         \
          int a = (BASE) + iy * (N) + ix;                                   \
          float4 bb = ((const float4*)pb_b)[a];                             \
          float c = ciou_pair(x1, y1, x2, y2, atan_t,                       \
                              bb.x, bb.y, bb.z, bb.w,                       \
                              atan_wh(bb.x, bb.y, bb.z, bb.w));             \
          float io = fminf(fmaxf(c, 0.f), 1.f);                             \
          float i2 = io * io;                                               \
          float i6 = i2 * i2 * i2;                                          \
          float sc = pc_b[(size_t)a * NC + tc];                             \
          float tm = i6 * sqrtf(sigmoid_fast(sc));                         \
          key = pack_key(tm, a);                                            \
        }                                                                   \
      }                                                                     \
      unsigned long long mask = __ballot(pred);                             \
      if (pred) {                                                           \
        int slot = nmine + __popcll(mask & ((1ULL << lane) - 1ULL));        \
        if (slot < CAPW) my[slot] = key;                                    \
      }                                                                     \
      nmine += __popcll(mask);                                              \
    }                                                                       \
  }
  LEVEL_LOOP(8, 80, 0)
  LEVEL_LOOP(16, 40, 6400)
  LEVEL_LOOP(32, 20, 8000)
#undef LEVEL_LOOP
  int n = nmine; if (n > CAPW) n = CAPW;   // slots 0..n-1 all initialized

  // 12 static u64 register slots per lane (12*64 = 768 = CAPW)
  u64 c0=0,c1=0,c2=0,c3=0,c4=0,c5=0,c6=0,c7=0,c8=0,c9=0,c10=0,c11=0;
  if (lane < n)            c0  = my[lane];
  if (lane + 64 < n)       c1  = my[lane + 64];
  if (lane + 128 < n)      c2  = my[lane + 128];
  if (lane + 192 < n)      c3  = my[lane + 192];
  if (lane + 256 < n)      c4  = my[lane + 256];
  if (lane + 320 < n)      c5  = my[lane + 320];
  if (lane + 384 < n)      c6  = my[lane + 384];
  if (lane + 448 < n)      c7  = my[lane + 448];
  if (lane + 512 < n)      c8  = my[lane + 512];
  if (lane + 576 < n)      c9  = my[lane + 576];
  if (lane + 640 < n)      c10 = my[lane + 640];
  if (lane + 704 < n)      c11 = my[lane + 704];

  // 10 rounds: 12-slot local max -> 6-step butterfly -> kill.  No barriers.
  u64 winner = 0;                  // lane k keeps round-k winner
  for (int k = 0; k < KTOP; k++) {
    u64 bk = c0;
    if (c1  > bk) bk = c1;   if (c2  > bk) bk = c2;
    if (c3  > bk) bk = c3;   if (c4  > bk) bk = c4;
    if (c5  > bk) bk = c5;   if (c6  > bk) bk = c6;
    if (c7  > bk) bk = c7;   if (c8  > bk) bk = c8;
    if (c9  > bk) bk = c9;   if (c10 > bk) bk = c10;
    if (c11 > bk) bk = c11;
#pragma unroll
    for (int off = 32; off > 0; off >>= 1) {
      u64 ok = __shfl_xor(bk, off);
      if (ok > bk) bk = ok;
    }
    if (lane == k) winner = bk;
    if (bk != 0) {                 // kill (keys unique; 0 kills nothing)
      if (c0  == bk) c0  = 0;  if (c1  == bk) c1  = 0;
      if (c2  == bk) c2  = 0;  if (c3  == bk) c3  = 0;
      if (c4  == bk) c4  = 0;  if (c5  == bk) c5  = 0;
      if (c6  == bk) c6  = 0;  if (c7  == bk) c7  = 0;
      if (c8  == bk) c8  = 0;  if (c9  == bk) c9  = 0;
      if (c10 == bk) c10 = 0;  if (c11 == bk) c11 = 0;
    }
  }

  // lanes 0..9 write winners; recompute clipped ciou (10 per wave, trivial)
  if (lane < KTOP) {
    u64 key = winner;
    float v = __uint_as_float((unsigned)(key >> 32));
    int ai = INT_MAX - (int)(key & 0xFFFFFFFFu);
    float io = 0.f;
    if (key != 0 && v > 0.f) {
      float4 bb = ((const float4*)pb_b)[ai];
      float c = ciou_pair(x1, y1, x2, y2, atan_t, bb.x, bb.y, bb.z, bb.w,
                          atan_wh(bb.x, bb.y, bb.z, bb.w));
      io = fminf(fmaxf(c, 0.f), 1.f);
    } else { ai = -1; v = 0.f; }
    size_t o = (size_t)row * KTOP + lane;
    top_val[o] = v; top_idx[o] = ai; top_iou[o] = io;
  }
}

// ---- K2: 4 entries per wave: shared dedup scan + per-entry loss terms ----
__global__ __launch_bounds__(256) void k_resolve(
    const float* __restrict__ target, const float* __restrict__ pcls,
    const float* __restrict__ pbox, const float* __restrict__ anchors,
    const float* __restrict__ top_val, const int* __restrict__ top_idx,
    const float* __restrict__ top_iou,
    float* __restrict__ as_tm, float* __restrict__ as_x,
    float* __restrict__ as_cio, int* __restrict__ as_u,
    unsigned* __restrict__ mtg, unsigned* __restrict__ mig)
{
  int wave = (blockIdx.x * 256 + threadIdx.x) >> 6;  // 0..5119
  int lane = threadIdx.x & 63;
  int e0 = wave * 4;               // 4 consecutive entries; NE%4==0 -> same b
  int b = e0 / NE;

  const float* bv = top_val + (size_t)b * NE;
  const int* bix = top_idx + (size_t)b * NE;

  int ea[4]; float ev[4];
  bool dead[4];
  int cnt[4]; int first[4];
#pragma unroll
  for (int j = 0; j < 4; j++) {
    int el = (e0 - b * NE) + j;
    ev[j] = bv[el]; ea[j] = bix[el];
    dead[j] = (ev[j] <= 0.f);
    cnt[j] = 0; first[j] = NE;
  }

  // single shared scan of this batch's 640 entries, tested against 4 anchors
  for (int s = lane; s < NE; s += 64) {
    float v2 = bv[s]; int a2 = bix[s];
    bool live = (v2 > 0.f);
#pragma unroll
    for (int j = 0; j < 4; j++) {
      if (live && a2 == ea[j]) { cnt[j]++; if (s < first[j]) first[j] = s; }
    }
  }
#pragma unroll
  for (int j = 0; j < 4; j++) {
    for (int off = 32; off > 0; off >>= 1) {
      cnt[j] += __shfl_xor(cnt[j], off);
      int of = __shfl_xor(first[j], off);
      first[j] = of < first[j] ? of : first[j];
    }
  }

#pragma unroll
  for (int j = 0; j < 4; j++) {
    int entry = e0 + j;
    int el = (e0 - b * NE) + j;
    if (!dead[j] && first[j] != el) dead[j] = true;  // not representative
    if (dead[j]) {
      if (lane == 0) { as_tm[entry] = 0.f; as_x[entry] = 0.f;
                       as_cio[entry] = 0.f; as_u[entry] = 0; }
      continue;
    }
    int a = ea[j];
    const float* pb = pbox + ((size_t)b * NA + a) * 4;
    int u; float tm = -1.f, io;
    if (cnt[j] == 1) {
      u = el / KTOP; tm = ev[j]; io = top_iou[entry];
    } else {
      // duplicate: argmax over 64 targets of clipped ciou, one per lane
      const float* tg = target + (size_t)(b * NT + lane) * 5;
      float tx1 = tg[1], ty1 = tg[2], tx2 = tg[3], ty2 = tg[4];
      float ta = atan_wh(tx1, ty1, tx2, ty2);
      float bx1 = pb[0], by1 = pb[1], bx2 = pb[2], by2 = pb[3];
      float pa = atan_wh(bx1, by1, bx2, by2);
      float c = ciou_pair(tx1, ty1, tx2, ty2, ta, bx1, by1, bx2, by2, pa);
      float cc = fminf(fmaxf(c, 0.f), 1.f);
      float best = cc; int bu = lane;
      for (int off = 32; off > 0; off >>= 1) {
        float ob = __shfl_xor(best, off);
        int ou = __shfl_xor(bu, off);
        if (ob > best || (ob == best && ou < bu)) { best = ob; bu = ou; }
      }
      u = bu; io = best;             // lowest-t tie-break == jnp.argmax
    }

    if (lane == 0) {
      const float* tgu = target + (size_t)(b * NT + u) * 5;
      float ux1 = tgu[1], uy1 = tgu[2], ux2 = tgu[3], uy2 = tgu[4];
      int cu = (int)tgu[0]; cu = cu < 0 ? 0 : (cu > NC - 1 ? NC - 1 : cu);
      float x = pcls[((size_t)b * NA + a) * NC + cu];
      if (cnt[j] != 1) {
        float2 an = ((const float2*)anchors)[a];
        float gm = (ux1 < an.x && an.x < ux2 && uy1 < an.y && an.y < uy2)
                       ? 1.f : 0.f;
        float i2 = io * io; float i6 = i2 * i2 * i2;
        float sig = sigmoid_fast(x);
        tm = gm * i6 * sqrtf(sig);
      }
      float bx1 = pb[0], by1 = pb[1], bx2 = pb[2], by2 = pb[3];
      float c = ciou_pair(ux1, uy1, ux2, uy2, atan_wh(ux1, uy1, ux2, uy2),
                          bx1, by1, bx2, by2, atan_wh(bx1, by1, bx2, by2));
      as_tm[entry] = tm; as_x[entry] = x; as_cio[entry] = 1.f - c; as_u[entry] = u;
      atomicMax(&mtg[b * NT + u], __float_as_uint(tm));  // non-neg floats
      atomicMax(&mig[b * NT + u], __float_as_uint(io));
    }
  }
}

// ---- K3: fused softplus sums + per-batch sums ----------------------------
__global__ __launch_bounds__(256) void k_bce_sums(
    const float* __restrict__ pcls,
    const float* __restrict__ as_tm, const float* __restrict__ as_x,
    const float* __restrict__ as_cio, const int* __restrict__ as_u,
    const unsigned* __restrict__ mtg, const unsigned* __restrict__ mig,
    double* __restrict__ bce_part, double* __restrict__ k2_part)
{
  int tid = threadIdx.x;
  __shared__ double red[256];

  if (blockIdx.x < BCE_BLOCKS) {
    const float4* p4 = (const float4*)pcls;
    const int n4 = NB * NA * NC / 4;  // 5,376,000
    double acc = 0.0;
    for (int i = blockIdx.x * 256 + tid; i < n4; i += BCE_BLOCKS * 256) {
      float4 v = p4[i];
      float p = (softplus_fast(v.x) + softplus_fast(v.y)) +
                (softplus_fast(v.z) + softplus_fast(v.w));
      acc += (double)p;
    }
    red[tid] = acc; __syncthreads();
    for (int off = 128; off > 0; off >>= 1) {
      if (tid < off) red[tid] += red[tid + off];
      __syncthreads();
    }
    if (tid == 0) bce_part[blockIdx.x] = red[0];
    return;
  }

  int b = blockIdx.x - BCE_BLOCKS;
  double s1 = 0.0, s2 = 0.0, s3 = 0.0;
  for (int e = tid; e < NE; e += 256) {
    size_t o = (size_t)b * NE + e;
    float tm = as_tm[o];
    int u = as_u[o];
    float maxt = __uint_as_float(mtg[b * NT + u]);
    float maxi = __uint_as_float(mig[b * NT + u]);
    float nrm = tm / (maxt + 1e-9f) * maxi;   // exact 0 for dead entries
    s1 += (double)nrm;
    s2 += (double)as_x[o] * (double)nrm;
    s3 += (double)(as_cio[o] * nrm);
  }
  red[tid] = s1; __syncthreads();
  for (int off = 128; off > 0; off >>= 1) {
    if (tid < off) red[tid] += red[tid + off];
    __syncthreads();
  }
  if (tid == 0) k2_part[b * 3 + 0] = red[0];
  __syncthreads();
  red[tid] = s2; __syncthreads();
  for (int off = 128; off > 0; off >>= 1) {
    if (tid < off) red[tid] += red[tid + off];
    __syncthreads();
  }
  if (tid == 0) k2_part[b * 3 + 1] = red[0];
  __syncthreads();
  red[tid] = s3; __syncthreads();
  for (int off = 128; off > 0; off >>= 1) {
    if (tid < off) red[tid] += red[tid + off];
    __syncthreads();
  }
  if (tid == 0) k2_part[b * 3 + 2] = red[0];
}

// ---- K4: combine everything ----------------------------------------------
__global__ __launch_bounds__(256) void k_final(const double* __restrict__ bce_part,
                                               const double* __restrict__ k2_part,
                                               float* __restrict__ out) {
  __shared__ double red[256];
  int tid = threadIdx.x;
  double s = 0.0;
  for (int i = tid; i < BCE_BLOCKS; i += 256) s += bce_part[i];
  red[tid] = s; __syncthreads();
  for (int off = 128; off > 0; off >>= 1) {
    if (tid < off) red[tid] += red[tid + off];
    __syncthreads();
  }
  double s4 = red[0]; __syncthreads();

  red[tid] = (tid < NB) ? k2_part[3 * tid + 0] : 0.0; __syncthreads();
  for (int off = 128; off > 0; off >>= 1) {
    if (tid < off) red[tid] += red[tid + off];
    __syncthreads();
  }
  double s1 = red[0]; __syncthreads();

  red[tid] = (tid < NB) ? k2_part[3 * tid + 1] : 0.0; __syncthreads();
  for (int off = 128; off > 0; off >>= 1) {
    if (tid < off) red[tid] += red[tid + off];
    __syncthreads();
  }
  double s2 = red[0]; __syncthreads();

  red[tid] = (tid < NB) ? k2_part[3 * tid + 2] : 0.0; __syncthreads();
  for (int off = 128; off > 0; off >>= 1) {
    if (tid < off) red[tid] += red[tid + off];
    __syncthreads();
  }
  double s3 = red[0];

  if (tid == 0) {
    double cn = fmax(s1, 1.0);
    out[0] = (float)(s3 / cn);         // loss_iou
    out[1] = (float)((s4 - s2) / cn);  // loss_cls
  }
}

extern "C" void kernel_launch(void* const* d_in, const int* in_sizes, int n_in,
                              void* d_out, int out_size, void* d_ws, size_t ws_size,
                              hipStream_t stream) {
  const float* target  = (const float*)d_in[0];  // [32,64,5]
  const float* pcls    = (const float*)d_in[1];  // [32,8400,80]
  const float* pbox    = (const float*)d_in[2];  // [32,8400,4]
  const float* anchors = (const float*)d_in[3];  // [8400,2]
  float* out = (float*)d_out;

  char* ws = (char*)d_ws;
  float*    top_val = (float*)ws;                    // 20480 f  =  81,920 B
  int*      top_idx = (int*)(ws + 81920);            //             81,920 B
  float*    top_iou = (float*)(ws + 163840);         //             81,920 B
  float*    as_tm   = (float*)(ws + 245760);         //             81,920 B
  float*    as_x    = (float*)(ws + 327680);         //             81,920 B
  float*    as_cio  = (float*)(ws + 409600);         //             81,920 B
  int*      as_u    = (int*)(ws + 491520);           //             81,920 B
  unsigned* mtg     = (unsigned*)(ws + 573440);      // 2048 u   =   8,192 B
  unsigned* mig     = (unsigned*)(ws + 581632);      //              8,192 B
  double*   k2_part = (double*)(ws + 589824);        // 96 d     =     768 B
  double*   k3_part = (double*)(ws + 590592);        // 2048 d   =  16,384 B
  // total ws use: 606,976 B

  k_topk<<<NB * NT / 4, 256, 0, stream>>>(target, pcls, pbox,
                                          top_val, top_idx, top_iou, mtg, mig);
  k_resolve<<<(NB * NE / 4 * 64) / 256, 256, 0, stream>>>(
      target, pcls, pbox, anchors, top_val, top_idx, top_iou,
      as_tm, as_x, as_cio, as_u, mtg, mig);
  k_bce_sums<<<BCE_BLOCKS + NB, 256, 0, stream>>>(
      pcls, as_tm, as_x, as_cio, as_u, mtg, mig, k3_part, k2_part);
  k_final<<<1, 256, 0, stream>>>(k3_part, k2_part, out);
}